// Round 7
// baseline (879.930 us; speedup 1.0000x reference)
//
#include <hip/hip_runtime.h>
#include <cstdint>
#include <cstddef>

#define T_STEPS 1024
#define GRID    512   // one batch element per block; 2 blocks/CU

typedef __attribute__((ext_vector_type(8))) _Float16 half8;
typedef __attribute__((ext_vector_type(4))) _Float16 half4;
typedef __attribute__((ext_vector_type(4))) float    f32x4;

static __device__ __forceinline__ float sigm(float x) {
  return __builtin_amdgcn_rcpf(1.0f + __expf(-x));
}
static __device__ __forceinline__ float tanh_(float x) {
  return 1.0f - 2.0f * __builtin_amdgcn_rcpf(__expf(2.0f * x) + 1.0f);
}

static __device__ __forceinline__ half8 load8(const float* s) {
  float4 a = ((const float4*)s)[0];
  float4 b = ((const float4*)s)[1];
  half8 h;
  h[0] = (_Float16)a.x; h[1] = (_Float16)a.y; h[2] = (_Float16)a.z; h[3] = (_Float16)a.w;
  h[4] = (_Float16)b.x; h[5] = (_Float16)b.y; h[6] = (_Float16)b.z; h[7] = (_Float16)b.w;
  return h;
}

// 256 threads (4 waves), grid 512, ONE batch element per block -> 2 independent
// blocks per CU; their phases interleave so barrier/latency stalls of one block
// are filled by the other's work (the R6 structure had 1 block/CU and nothing
// to overlap with).
// Waves 0-1: L1, waves 2-3: L2. Wave owns 8 N-tiles: tile j -> gate tt=j>>1,
// unit-group un=j&1, gate row r = tt*64 + wh*32 + un*16 + col (wh = wave within
// layer). Batch row at MFMA A-row 0 -> D reg0 lanes 0-15; in-wave acts on
// lanes 0-15, 2 units per lane (c0,c1 in regs).
// x: bulk-prefetched 16 steps at a time; global load issued at p%16==0, held in
// regs, staged to LDS at p%16==8 (8-phase slack -> no barrier vmcnt stall).
// L1 pre-reads next x-frag and pre-issues the 8 x-kstep MFMAs before the
// barrier (x buffer is stable across the barrier).
// LDS padding: hstate buf stride 272B, xbig slot stride 80B -> all accesses
// <=2-way bank aliased (free per m136).
// MFMA layouts (m89/m120-verified): A[m=l&15][k=(l>>4)*8+j];
// B[k=(l>>4)*8+j][n=l&15]; D[row=(l>>4)*4+reg][col=l&15].
__global__ __launch_bounds__(256, 2) void lstm_fused(
    const float* __restrict__ x,
    const float* __restrict__ w_ih1, const float* __restrict__ w_hh1,
    const float* __restrict__ b_ih1, const float* __restrict__ b_hh1,
    const float* __restrict__ w_ih2, const float* __restrict__ w_hh2,
    const float* __restrict__ b_ih2, const float* __restrict__ b_hh2,
    const float* __restrict__ fc1_w, const float* __restrict__ fc1_b,
    const float* __restrict__ fc2_w, const float* __restrict__ fc2_b,
    const float* __restrict__ ln_g, const float* __restrict__ ln_b,
    float* __restrict__ out)
{
  __shared__ __align__(16) _Float16 hstate[2][136];   // [buf][h1(64)|h2(64)|pad]
  __shared__ __align__(16) _Float16 xbig[2][16][40];  // [buf][slot][x(32)|pad]
  __shared__ __align__(16) float hfin[64];
  __shared__ __align__(16) float y1s[128];
  __shared__ __align__(16) float y2s[128];
  __shared__ float redmu, redrs;

  const int t   = threadIdx.x;
  const int b   = blockIdx.x;
  const int l   = t & 63;
  const int w   = t >> 6;       // wave 0..3
  const int ly  = w >> 1;       // 0=L1, 1=L2
  const int wh  = w & 1;        // wave within layer
  const int col = l & 15;
  const int q   = l >> 4;       // quad

  // ---- init: zero h-state (both buffers) ----
  for (int i = t; i < 272; i += 256) ((_Float16*)hstate)[i] = (_Float16)0.0f;

  // ---- stationary weights -> B fragments wb[tile][kstep] ----
  half8 wb[8][4];
  {
    const int ko = q * 8;
    #pragma unroll
    for (int j = 0; j < 8; ++j) {
      const int tt = j >> 1, un = j & 1;
      const int r = tt * 64 + wh * 32 + un * 16 + col;
      if (ly == 0) {
        wb[j][0] = load8(w_ih1 + r * 32 + ko);        // k 0..31  x
        wb[j][1] = load8(w_hh1 + r * 64 + ko);        // h1 lo
        wb[j][2] = load8(w_hh1 + r * 64 + 32 + ko);   // h1 hi
      } else {
        wb[j][0] = load8(w_ih2 + r * 64 + ko);        // h1 lo
        wb[j][1] = load8(w_ih2 + r * 64 + 32 + ko);   // h1 hi
        wb[j][2] = load8(w_hh2 + r * 64 + ko);        // h2 lo
        wb[j][3] = load8(w_hh2 + r * 64 + 32 + ko);   // h2 hi
      }
    }
  }

  // ---- act-lane setup (lanes 0-15): units u0 = wh*32+col, u1 = u0+16 ----
  const int u0 = wh * 32 + col;
  float bia[2][4];
  {
    const float* bi_ = ly ? b_ih2 : b_ih1;
    const float* bh_ = ly ? b_hh2 : b_hh1;
    #pragma unroll
    for (int tt = 0; tt < 4; ++tt) {
      bia[0][tt] = bi_[tt * 64 + u0]      + bh_[tt * 64 + u0];
      bia[1][tt] = bi_[tt * 64 + u0 + 16] + bh_[tt * 64 + u0 + 16];
    }
  }
  const int hoff = ly ? 64 : 0;

  // ---- bulk x-prefetch lanes: lanes 32-63 of all 4 waves (128 lanes) ----
  const bool isx = (l >= 32);
  const int g  = w * 32 + (l - 32);   // 0..127
  const int fs = g >> 3;              // step-in-window 0..15
  const int fe = g & 7;               // float4 index 0..7
  const float* xsrc = x + (size_t)b * T_STEPS * 32 + fe * 4;

  // initial window: steps 0..15 -> xbig buf0
  if (isx) {
    const float4 v = *(const float4*)(xsrc + (size_t)fs * 32);
    half4 h; h[0] = (_Float16)v.x; h[1] = (_Float16)v.y; h[2] = (_Float16)v.z; h[3] = (_Float16)v.w;
    *(half4*)((char*)xbig + fs * 80 + fe * 8) = h;
  }
  __syncthreads();

  const char* xrdbase = (const char*)xbig + q * 16;
  const char* hrdbase = (const char*)hstate + q * 16;

  // pre-issue phase-0 x-kstep MFMAs (L1)
  f32x4 accp[8];
  if (ly == 0) {
    const half8 ax = *(const half8*)xrdbase;   // buf0 slot0 = x_0
    #pragma unroll
    for (int j = 0; j < 8; ++j)
      accp[j] = __builtin_amdgcn_mfma_f32_16x16x32_f16(ax, wb[j][0], (f32x4){0.f,0.f,0.f,0.f}, 0, 0, 0);
  }

  float4 xv = make_float4(0.f, 0.f, 0.f, 0.f);
  float c0 = 0.0f, c1 = 0.0f;

  for (int p = 0; p <= T_STEPS; ++p) {
    const int rd = (p + 1) & 1;
    const int wr = p & 1;

    // issue next-window global loads right after the barrier (8-phase slack)
    if (isx && (p & 15) == 0 && (p + 16 + fs) < T_STEPS)
      xv = *(const float4*)(xsrc + (size_t)(p + 16 + fs) * 32);

    // ---- h fragments + MFMAs ----
    const char* hb = hrdbase + rd * 272;
    f32x4 acc[8];
    if (ly == 0) {
      const half8 a1 = *(const half8*)(hb);        // h1 lo
      const half8 a2 = *(const half8*)(hb + 64);   // h1 hi
      #pragma unroll
      for (int j = 0; j < 8; ++j) {
        acc[j] = __builtin_amdgcn_mfma_f32_16x16x32_f16(a1, wb[j][1], accp[j], 0, 0, 0);
        acc[j] = __builtin_amdgcn_mfma_f32_16x16x32_f16(a2, wb[j][2], acc[j], 0, 0, 0);
      }
    } else {
      const half8 a0 = *(const half8*)(hb);
      const half8 a1 = *(const half8*)(hb + 64);
      const half8 a2 = *(const half8*)(hb + 128);
      const half8 a3 = *(const half8*)(hb + 192);
      #pragma unroll
      for (int j = 0; j < 8; ++j) {
        f32x4 a = __builtin_amdgcn_mfma_f32_16x16x32_f16(a0, wb[j][0], (f32x4){0.f,0.f,0.f,0.f}, 0, 0, 0);
        a = __builtin_amdgcn_mfma_f32_16x16x32_f16(a1, wb[j][1], a, 0, 0, 0);
        a = __builtin_amdgcn_mfma_f32_16x16x32_f16(a2, wb[j][2], a, 0, 0, 0);
        acc[j] = __builtin_amdgcn_mfma_f32_16x16x32_f16(a3, wb[j][3], a, 0, 0, 0);
      }
    }

    // ---- in-wave activations: lanes 0-15, 2 units each ----
    if (l < 16 && (ly == 0 || p > 0)) {
      const float gi0 = sigm (acc[0][0] + bia[0][0]);
      const float gf0 = sigm (acc[2][0] + bia[0][1]);
      const float gg0 = tanh_(acc[4][0] + bia[0][2]);
      const float go0 = sigm (acc[6][0] + bia[0][3]);
      c0 = gf0 * c0 + gi0 * gg0;
      const float h0 = go0 * tanh_(c0);
      const float gi1 = sigm (acc[1][0] + bia[1][0]);
      const float gf1 = sigm (acc[3][0] + bia[1][1]);
      const float gg1 = tanh_(acc[5][0] + bia[1][2]);
      const float go1 = sigm (acc[7][0] + bia[1][3]);
      c1 = gf1 * c1 + gi1 * gg1;
      const float h1v = go1 * tanh_(c1);
      hstate[wr][hoff + u0]      = (_Float16)h0;
      hstate[wr][hoff + u0 + 16] = (_Float16)h1v;
      if (ly == 1 && p == T_STEPS) { hfin[u0] = h0; hfin[u0 + 16] = h1v; }
    }

    // ---- pre-read next x-frag + pre-issue x-kstep MFMAs (L1) ----
    if (ly == 0 && p < T_STEPS) {
      const int pn = p + 1;
      const half8 ax = *(const half8*)(xrdbase + ((pn >> 4) & 1) * 1280 + (pn & 15) * 80);
      #pragma unroll
      for (int j = 0; j < 8; ++j)
        accp[j] = __builtin_amdgcn_mfma_f32_16x16x32_f16(ax, wb[j][0], (f32x4){0.f,0.f,0.f,0.f}, 0, 0, 0);
    }

    // ---- stage the register-held x window (loaded 8 phases ago) ----
    if (isx && (p & 15) == 8 && (p + 8 + fs) < T_STEPS) {
      half4 h; h[0] = (_Float16)xv.x; h[1] = (_Float16)xv.y; h[2] = (_Float16)xv.z; h[3] = (_Float16)xv.w;
      *(half4*)((char*)xbig + (((p >> 4) + 1) & 1) * 1280 + fs * 80 + fe * 8) = h;
    }
    __syncthreads();
  }

  // ---- head: y = LN(relu(hT@fc1^T+b1)@fc2^T+b2) ----
  if (t < 128) {
    float a = fc1_b[t];
    const float4* w4 = (const float4*)(fc1_w + t * 64);
    const float4* h4 = (const float4*)hfin;
    #pragma unroll
    for (int qq = 0; qq < 16; ++qq) {
      float4 wv = w4[qq]; float4 hv = h4[qq];
      a += wv.x * hv.x + wv.y * hv.y + wv.z * hv.z + wv.w * hv.w;
    }
    y1s[t] = fmaxf(a, 0.0f);
  }
  __syncthreads();
  if (t < 128) {
    float a = fc2_b[t];
    const float4* w4 = (const float4*)(fc2_w + t * 128);
    const float4* y4 = (const float4*)y1s;
    #pragma unroll
    for (int qq = 0; qq < 32; ++qq) {
      float4 wv = w4[qq]; float4 yv = y4[qq];
      a += wv.x * yv.x + wv.y * yv.y + wv.z * yv.z + wv.w * yv.w;
    }
    y2s[t] = a;
  }
  __syncthreads();
  if (t < 64) {
    float s  = y2s[t] + y2s[t + 64];
    float qs = y2s[t] * y2s[t] + y2s[t + 64] * y2s[t + 64];
    #pragma unroll
    for (int off = 32; off > 0; off >>= 1) {
      s  += __shfl_down(s, off, 64);
      qs += __shfl_down(qs, off, 64);
    }
    if (t == 0) {
      const float mu  = s * (1.0f / 128.0f);
      const float var = qs * (1.0f / 128.0f) - mu * mu;
      redmu = mu;
      redrs = rsqrtf(var + 1e-5f);
    }
  }
  __syncthreads();
  if (t < 128) {
    out[(size_t)b * 128 + t] = (y2s[t] - redmu) * redrs * ln_g[t] + ln_b[t];
  }
}

extern "C" void kernel_launch(void* const* d_in, const int* in_sizes, int n_in,
                              void* d_out, int out_size, void* d_ws, size_t ws_size,
                              hipStream_t stream) {
  const float* x     = (const float*)d_in[0];
  const float* w_ih1 = (const float*)d_in[1];
  const float* w_hh1 = (const float*)d_in[2];
  const float* b_ih1 = (const float*)d_in[3];
  const float* b_hh1 = (const float*)d_in[4];
  const float* w_ih2 = (const float*)d_in[5];
  const float* w_hh2 = (const float*)d_in[6];
  const float* b_ih2 = (const float*)d_in[7];
  const float* b_hh2 = (const float*)d_in[8];
  const float* fc1_w = (const float*)d_in[9];
  const float* fc1_b = (const float*)d_in[10];
  const float* fc2_w = (const float*)d_in[11];
  const float* fc2_b = (const float*)d_in[12];
  const float* ln_g  = (const float*)d_in[13];
  const float* ln_b  = (const float*)d_in[14];
  float* out = (float*)d_out;

  lstm_fused<<<GRID, 256, 0, stream>>>(x, w_ih1, w_hh1, b_ih1, b_hh1,
                                       w_ih2, w_hh2, b_ih2, b_hh2,
                                       fc1_w, fc1_b, fc2_w, fc2_b,
                                       ln_g, ln_b, out);
}

// Round 8
// 577.115 us; speedup vs baseline: 1.5247x; 1.5247x over previous
//
#include <hip/hip_runtime.h>
#include <cstdint>
#include <cstddef>

#define T_STEPS 1024
#define NBLK    256   // 512 batch / 2 per block; 1 block per CU

typedef __attribute__((ext_vector_type(8))) _Float16 half8;
typedef __attribute__((ext_vector_type(4))) _Float16 half4;
typedef __attribute__((ext_vector_type(4))) float    f32x4;

static __device__ __forceinline__ float sigm(float x) {
  return __builtin_amdgcn_rcpf(1.0f + __expf(-x));
}
static __device__ __forceinline__ float tanh_(float x) {
  return 1.0f - 2.0f * __builtin_amdgcn_rcpf(__expf(2.0f * x) + 1.0f);
}

static __device__ __forceinline__ half8 load8(const float* s) {
  float4 a = ((const float4*)s)[0];
  float4 b = ((const float4*)s)[1];
  half8 h;
  h[0] = (_Float16)a.x; h[1] = (_Float16)a.y; h[2] = (_Float16)a.z; h[3] = (_Float16)a.w;
  h[4] = (_Float16)b.x; h[5] = (_Float16)b.y; h[6] = (_Float16)b.z; h[7] = (_Float16)b.w;
  return h;
}
static __device__ __forceinline__ half8 zero8() {
  half8 h;
  #pragma unroll
  for (int j = 0; j < 8; ++j) h[j] = (_Float16)0.0f;
  return h;
}

// Workgroup barrier that drains ONLY lgkmcnt (LDS) — leaves global loads in
// flight across the barrier. LDS producer->consumer visibility is preserved
// (every wave drains its ds_writes before s_barrier); the bulk-x global loads
// are waited only at their register use (staging, 8 phases later), so their
// ~900-cycle HBM latency is fully hidden instead of being force-drained by
// __syncthreads' vmcnt(0) at every barrier.
static __device__ __forceinline__ void barrier_lds() {
  __asm__ volatile("s_waitcnt lgkmcnt(0)\n\ts_barrier" ::: "memory");
}

// R6 structure (best: 586us), grid 256 x 512 threads, batch rows {2b,2b+1} at
// MFMA A-rows 0 and 4 (D reg0: batch0 lanes 0-15, batch1 lanes 16-31 -> no
// shuffle). Waves 0-3: L1, 4-7: L2; wave owns all 4 gate types of 16 units
// (tile tt = gate, row = tt*64 + wq*16 + col) -> in-wave activations, ONE
// barrier per phase. L1 pre-reads x-frag and pre-issues x-kstep MFMAs before
// the barrier. Fixes vs R6:
//  (1) padded LDS: xbig slot stride 160B (was 128B bank-aligned -> 2.75e7
//      conflicts), hstate batch stride 272B.
//  (2) lgkm-only loop barrier (see barrier_lds) -> bulk-x loads float.
// MFMA layouts (m89/m120-verified): A[m=l&15][k=(l>>4)*8+j];
// B[k=(l>>4)*8+j][n=l&15]; D[row=(l>>4)*4+reg][col=l&15].
__global__ __launch_bounds__(512, 2) void lstm_fused(
    const float* __restrict__ x,
    const float* __restrict__ w_ih1, const float* __restrict__ w_hh1,
    const float* __restrict__ b_ih1, const float* __restrict__ b_hh1,
    const float* __restrict__ w_ih2, const float* __restrict__ w_hh2,
    const float* __restrict__ b_ih2, const float* __restrict__ b_hh2,
    const float* __restrict__ fc1_w, const float* __restrict__ fc1_b,
    const float* __restrict__ fc2_w, const float* __restrict__ fc2_b,
    const float* __restrict__ ln_g, const float* __restrict__ ln_b,
    float* __restrict__ out)
{
  __shared__ __align__(16) _Float16 hstate[2][2][136];   // [buf][batch][h1(64)|h2(64)|pad]
  __shared__ __align__(16) _Float16 xbig[2][16][2][40];  // [buf][slot][batch][x(32)|pad]
  __shared__ __align__(16) float hfin[2][64];
  __shared__ __align__(16) float y1s[2][128];
  __shared__ __align__(16) float y2s[2][128];
  __shared__ float redmu[2], redrs[2];

  const int t   = threadIdx.x;
  const int b   = blockIdx.x;
  const int l   = t & 63;
  const int w   = t >> 6;       // wave 0..7
  const int ly  = w >> 2;       // 0=L1, 1=L2
  const int wq  = w & 3;        // unit group
  const int col = l & 15;
  const int q   = l >> 4;       // quad
  const int m   = l & 15;       // A row this lane feeds
  const int bm  = (m >> 2) & 1; // batch whose A-row this lane serves

  // ---- init: zero h-state (both buffers, incl. pad) ----
  for (int i = t; i < 544; i += 512) ((_Float16*)hstate)[i] = (_Float16)0.0f;
  // ---- init: preload x[0..16) into xbig buf0 ----
  if (t < 256) {
    const int b0 = t >> 7, r0 = t & 127, tr0 = r0 >> 3, ii0 = r0 & 7;
    const float4 v = *(const float4*)(x + ((size_t)(2 * b + b0) * T_STEPS + tr0) * 32 + ii0 * 4);
    half4 h; h[0] = (_Float16)v.x; h[1] = (_Float16)v.y; h[2] = (_Float16)v.z; h[3] = (_Float16)v.w;
    *(half4*)((char*)xbig + tr0 * 160 + b0 * 80 + ii0 * 8) = h;
  }

  // ---- stationary weights -> B fragments wb[tile=gate][kstep] ----
  half8 wb[4][4];
  {
    const int ko = q * 8;
    #pragma unroll
    for (int tt = 0; tt < 4; ++tt) {
      const int r = tt * 64 + wq * 16 + col;
      if (ly == 0) {
        wb[tt][0] = load8(w_ih1 + r * 32 + ko);        // x
        wb[tt][1] = load8(w_hh1 + r * 64 + ko);        // h1 lo
        wb[tt][2] = load8(w_hh1 + r * 64 + 32 + ko);   // h1 hi
        wb[tt][3] = zero8();
      } else {
        wb[tt][0] = load8(w_ih2 + r * 64 + ko);        // h1 lo
        wb[tt][1] = load8(w_ih2 + r * 64 + 32 + ko);   // h1 hi
        wb[tt][2] = load8(w_hh2 + r * 64 + ko);        // h2 lo
        wb[tt][3] = load8(w_hh2 + r * 64 + 32 + ko);   // h2 hi
      }
    }
  }

  // ---- act-lane setup (lanes 0-31): unit u, batch = l>>4 ----
  const int u = wq * 16 + col;
  float bia[4];
  {
    const float* bi_ = ly ? b_ih2 : b_ih1;
    const float* bh_ = ly ? b_hh2 : b_hh1;
    #pragma unroll
    for (int k2 = 0; k2 < 4; ++k2) bia[k2] = bi_[k2 * 64 + u] + bh_[k2 * 64 + u];
  }
  const int hoff = ly ? 64 : 0;
  const int abm  = l >> 4;       // act batch (lanes 0-31)

  // ---- bulk x-prefetch lane mapping (lanes 32-63, all 8 waves = 256 lanes) ----
  const bool isx = (l >= 32);
  const int g   = w * 32 + (l - 32);      // 0..255
  const int xbm = g >> 7, xr = g & 127, xtr = xr >> 3, xii = xr & 7;
  const float* xsrc = x + ((size_t)(2 * b + xbm) * T_STEPS) * 32 + xii * 4;

  // per-lane LDS bases
  const char* xbase  = (const char*)xbig + bm * 80 + q * 16;      // + buf*2560 + slot*160
  const char* hbase0 = (const char*)hstate + bm * 272 + q * 16;   // + buf*544 (+64/128/192 ksteps)

  __syncthreads();

  // ---- pre-issue phase-0 x-kstep MFMAs (L1) ----
  f32x4 accp[4];
  #pragma unroll
  for (int tt = 0; tt < 4; ++tt) accp[tt] = (f32x4){0.f, 0.f, 0.f, 0.f};
  if (ly == 0) {
    const half8 a0 = *(const half8*)(xbase);   // buf0, slot0 = x_0
    #pragma unroll
    for (int tt = 0; tt < 4; ++tt)
      accp[tt] = __builtin_amdgcn_mfma_f32_16x16x32_f16(a0, wb[tt][0], accp[tt], 0, 0, 0);
  }

  float4 xv = make_float4(0.f, 0.f, 0.f, 0.f);
  float c = 0.0f;

  for (int p = 0; p <= T_STEPS; ++p) {
    const int rd = (p + 1) & 1;
    const int wr = p & 1;

    // issue bulk x loads (value consumed at p%16==8 -> 8-phase slack; with the
    // lgkm-only barrier these stay in flight across barriers)
    if (isx && (p & 15) == 0 && (p + 16 + xtr) < T_STEPS)
      xv = *(const float4*)(xsrc + (size_t)(p + 16 + xtr) * 32);

    // ---- h-fragments + chained MFMAs ----
    const char* hb = hbase0 + rd * 544;
    f32x4 acc[4];
    if (ly == 0) {
      const half8 a1 = *(const half8*)(hb);        // h1 lo
      const half8 a2 = *(const half8*)(hb + 64);   // h1 hi
      #pragma unroll
      for (int tt = 0; tt < 4; ++tt) {
        acc[tt] = __builtin_amdgcn_mfma_f32_16x16x32_f16(a1, wb[tt][1], accp[tt], 0, 0, 0);
        acc[tt] = __builtin_amdgcn_mfma_f32_16x16x32_f16(a2, wb[tt][2], acc[tt], 0, 0, 0);
      }
    } else {
      const half8 a0 = *(const half8*)(hb);         // h1 lo
      const half8 a1 = *(const half8*)(hb + 64);    // h1 hi
      const half8 a2 = *(const half8*)(hb + 128);   // h2 lo
      const half8 a3 = *(const half8*)(hb + 192);   // h2 hi
      #pragma unroll
      for (int tt = 0; tt < 4; ++tt) {
        f32x4 a = __builtin_amdgcn_mfma_f32_16x16x32_f16(a0, wb[tt][0], (f32x4){0.f,0.f,0.f,0.f}, 0, 0, 0);
        a = __builtin_amdgcn_mfma_f32_16x16x32_f16(a1, wb[tt][1], a, 0, 0, 0);
        a = __builtin_amdgcn_mfma_f32_16x16x32_f16(a2, wb[tt][2], a, 0, 0, 0);
        acc[tt] = __builtin_amdgcn_mfma_f32_16x16x32_f16(a3, wb[tt][3], a, 0, 0, 0);
      }
    }

    // ---- in-wave activations: lanes 0-31, reg0 (batch = l>>4) ----
    if (l < 32 && (ly == 0 || p > 0)) {
      const float gi = sigm(acc[0][0] + bia[0]);
      const float gf = sigm(acc[1][0] + bia[1]);
      const float gg = tanh_(acc[2][0] + bia[2]);
      const float go = sigm(acc[3][0] + bia[3]);
      c = gf * c + gi * gg;
      const float hv = go * tanh_(c);
      hstate[wr][abm][hoff + u] = (_Float16)hv;
      if (ly == 1 && p == T_STEPS) hfin[abm][u] = hv;   // h2_{T-1}
    }

    // ---- pre-read next x-frag + pre-issue x-kstep MFMAs (L1) ----
    if (ly == 0 && p < T_STEPS) {
      const int pn = p + 1;
      const half8 a0n = *(const half8*)(xbase + ((pn >> 4) & 1) * 2560 + (pn & 15) * 160);
      #pragma unroll
      for (int tt = 0; tt < 4; ++tt)
        accp[tt] = __builtin_amdgcn_mfma_f32_16x16x32_f16(a0n, wb[tt][0], (f32x4){0.f,0.f,0.f,0.f}, 0, 0, 0);
    }

    // ---- stage the register-held x window (loaded 8 phases ago) ----
    if (isx && (p & 15) == 8 && (p + 8 + xtr) < T_STEPS) {
      half4 h; h[0] = (_Float16)xv.x; h[1] = (_Float16)xv.y; h[2] = (_Float16)xv.z; h[3] = (_Float16)xv.w;
      *(half4*)((char*)xbig + (((p >> 4) + 1) & 1) * 2560 + xtr * 160 + xbm * 80 + xii * 8) = h;
    }
    barrier_lds();
  }

  __syncthreads();   // full drain before epilogue

  // ---- head: y = LN(relu(hT@fc1^T+b1)@fc2^T+b2), 2 batch rows ----
  if (t < 256) {
    const int bi = t >> 7, j = t & 127;
    float a = fc1_b[j];
    const float4* w4 = (const float4*)(fc1_w + j * 64);
    const float4* h4 = (const float4*)hfin[bi];
    #pragma unroll
    for (int qq = 0; qq < 16; ++qq) {
      float4 wv = w4[qq]; float4 hv = h4[qq];
      a += wv.x * hv.x + wv.y * hv.y + wv.z * hv.z + wv.w * hv.w;
    }
    y1s[bi][j] = fmaxf(a, 0.0f);
  }
  __syncthreads();
  if (t < 256) {
    const int bi = t >> 7, j = t & 127;
    float a = fc2_b[j];
    const float4* w4 = (const float4*)(fc2_w + j * 128);
    const float4* y4 = (const float4*)y1s[bi];
    #pragma unroll
    for (int qq = 0; qq < 32; ++qq) {
      float4 wv = w4[qq]; float4 yv = y4[qq];
      a += wv.x * yv.x + wv.y * yv.y + wv.z * yv.z + wv.w * yv.w;
    }
    y2s[bi][j] = a;
  }
  __syncthreads();
  if (t < 128) {
    const int bi = t >> 6, jj = t & 63;
    float s  = y2s[bi][jj] + y2s[bi][64 + jj];
    float qs = y2s[bi][jj] * y2s[bi][jj] + y2s[bi][64 + jj] * y2s[bi][64 + jj];
    #pragma unroll
    for (int off = 32; off > 0; off >>= 1) {
      s  += __shfl_down(s, off, 64);
      qs += __shfl_down(qs, off, 64);
    }
    if (jj == 0) {
      const float mu  = s * (1.0f / 128.0f);
      const float var = qs * (1.0f / 128.0f) - mu * mu;
      redmu[bi] = mu;
      redrs[bi] = rsqrtf(var + 1e-5f);
    }
  }
  __syncthreads();
  if (t < 256) {
    const int bi = t >> 7, j = t & 127;
    out[(size_t)(2 * b + bi) * 128 + j] =
        (y2s[bi][j] - redmu[bi]) * redrs[bi] * ln_g[j] + ln_b[j];
  }
}

extern "C" void kernel_launch(void* const* d_in, const int* in_sizes, int n_in,
                              void* d_out, int out_size, void* d_ws, size_t ws_size,
                              hipStream_t stream) {
  const float* x     = (const float*)d_in[0];
  const float* w_ih1 = (const float*)d_in[1];
  const float* w_hh1 = (const float*)d_in[2];
  const float* b_ih1 = (const float*)d_in[3];
  const float* b_hh1 = (const float*)d_in[4];
  const float* w_ih2 = (const float*)d_in[5];
  const float* w_hh2 = (const float*)d_in[6];
  const float* b_ih2 = (const float*)d_in[7];
  const float* b_hh2 = (const float*)d_in[8];
  const float* fc1_w = (const float*)d_in[9];
  const float* fc1_b = (const float*)d_in[10];
  const float* fc2_w = (const float*)d_in[11];
  const float* fc2_b = (const float*)d_in[12];
  const float* ln_g  = (const float*)d_in[13];
  const float* ln_b  = (const float*)d_in[14];
  float* out = (float*)d_out;

  lstm_fused<<<NBLK, 512, 0, stream>>>(x, w_ih1, w_hh1, b_ih1, b_hh1,
                                       w_ih2, w_hh2, b_ih2, b_hh2,
                                       fc1_w, fc1_b, fc2_w, fc2_b,
                                       ln_g, ln_b, out);
}